// Round 2
// baseline (114.767 us; speedup 1.0000x reference)
//
#include <hip/hip_runtime.h>
#include <hip/hip_bf16.h>

typedef __bf16 bf16_t;
typedef __bf16 bf16x4 __attribute__((ext_vector_type(4)));
typedef __bf16 bf16x8 __attribute__((ext_vector_type(8)));
typedef float f32x4 __attribute__((ext_vector_type(4)));

#define S_LEN 2048
#define DMODEL 1024
#define NHEADS 16
#define HDIM 64
#define BROWS 4096  // B * S

__device__ __forceinline__ void async16(const void* g, void* l) {
  __builtin_amdgcn_global_load_lds(
      (const __attribute__((address_space(1))) void*)g,
      (__attribute__((address_space(3))) void*)l, 16, 0, 0);
}

// ---------------- f32 -> bf16 conversion (vectorized) ----------------
__global__ __launch_bounds__(256) void cvt_kernel(const float* __restrict__ src,
                                                  bf16_t* __restrict__ dst,
                                                  int n4) {
  const int i = blockIdx.x * 256 + threadIdx.x;
  if (i >= n4) return;
  const float4 v = *(const float4*)(src + (size_t)i * 4);
  bf16x4 o;
  o[0] = (bf16_t)v.x;
  o[1] = (bf16_t)v.y;
  o[2] = (bf16_t)v.z;
  o[3] = (bf16_t)v.w;
  *(bf16x4*)(dst + (size_t)i * 4) = o;
}

// C[m,n] = sum_k A[m,k] * W[n,k] + bias[n]
// A: [4096,1024] bf16 row-major (ws). W: [1024,1024] bf16 row-major (ws).
// Tile 128x128, BK=32, 4 waves (2x2), each wave 64x64 = 4x4 frags of 16x16x32.
template <typename OutT>
__device__ __forceinline__ void gemm_body(
    const bf16_t* __restrict__ A, const bf16_t* __restrict__ W,
    const float* __restrict__ bias, OutT* __restrict__ C, int m0, int n0) {
  constexpr int Kd = 1024, Nd = 1024, BK = 32, NT = Kd / BK;
  __shared__ bf16_t ldsA[2][128 * BK];
  __shared__ bf16_t ldsB[2][128 * BK];

  const int tid = threadIdx.x;
  const int lane = tid & 63;
  const int wave = tid >> 6;
  const int wr = wave >> 1;  // wave row (0..1)
  const int wc = wave & 1;   // wave col (0..1)

  f32x4 acc[4][4] = {};

  const int fr = lane & 15;        // fragment row (A) / col (B)
  const int ko = (lane >> 4) * 8;  // k offset within BK

  auto stage = [&](int buf, int t) {
    const int k0 = t * BK;
#pragma unroll
    for (int p = 0; p < 2; ++p) {
      const int off = (p * 256 + tid) * 16;  // byte offset into 8KB tile
      const int row = off >> 6;              // 64 B per row (BK=32 bf16)
      const int kb = off & 63;
      async16((const char*)(A + (size_t)(m0 + row) * Kd + k0) + kb,
              (char*)ldsA[buf] + off);
      async16((const char*)(W + (size_t)(n0 + row) * Kd + k0) + kb,
              (char*)ldsB[buf] + off);
    }
  };

  auto compute = [&](int buf) {
    bf16x8 af[4], bfr[4];
#pragma unroll
    for (int i = 0; i < 4; ++i)
      af[i] = *(const bf16x8*)(ldsA[buf] + (wr * 64 + i * 16 + fr) * BK + ko);
#pragma unroll
    for (int j = 0; j < 4; ++j)
      bfr[j] = *(const bf16x8*)(ldsB[buf] + (wc * 64 + j * 16 + fr) * BK + ko);
#pragma unroll
    for (int i = 0; i < 4; ++i)
#pragma unroll
      for (int j = 0; j < 4; ++j)
        acc[i][j] = __builtin_amdgcn_mfma_f32_16x16x32_bf16(af[i], bfr[j],
                                                            acc[i][j], 0, 0, 0);
  };

  stage(0, 0);
  __syncthreads();
#pragma unroll 1
  for (int t = 0; t < NT; ++t) {
    if (t + 1 < NT) stage((t + 1) & 1, t + 1);
    compute(t & 1);
    __syncthreads();
  }

  // Epilogue: C/D layout col = lane&15, row = (lane>>4)*4 + reg  [m89]
  const int cr = (lane >> 4) * 4;
#pragma unroll
  for (int j = 0; j < 4; ++j) {
    const int col = n0 + wc * 64 + j * 16 + fr;
    const float bv = bias[col];
#pragma unroll
    for (int i = 0; i < 4; ++i) {
#pragma unroll
      for (int r = 0; r < 4; ++r) {
        const int row = m0 + wr * 64 + i * 16 + cr + r;
        C[(size_t)row * Nd + col] = (OutT)(acc[i][j][r] + bv);
      }
    }
  }
}

__global__ __launch_bounds__(256) void gemm_qkv_kernel(
    const bf16_t* __restrict__ xb, const bf16_t* __restrict__ Wqb,
    const bf16_t* __restrict__ Wkb, const bf16_t* __restrict__ Wvb,
    const float* __restrict__ bq, const float* __restrict__ bk,
    const float* __restrict__ bv, bf16_t* __restrict__ Q,
    bf16_t* __restrict__ K, bf16_t* __restrict__ V) {
  const int mat = blockIdx.y >> 3;  // 0=Q 1=K 2=V
  const int nt = blockIdx.y & 7;
  const bf16_t* W = (mat == 0) ? Wqb : (mat == 1) ? Wkb : Wvb;
  const float* bias = (mat == 0) ? bq : (mat == 1) ? bk : bv;
  bf16_t* C = (mat == 0) ? Q : (mat == 1) ? K : V;
  gemm_body<bf16_t>(xb, W, bias, C, blockIdx.x * 128, nt * 128);
}

__global__ __launch_bounds__(256) void gemm_o_kernel(
    const bf16_t* __restrict__ ctx, const bf16_t* __restrict__ Wob,
    const float* __restrict__ bo, float* __restrict__ out) {
  gemm_body<float>(ctx, Wob, bo, out, blockIdx.x * 128, blockIdx.y * 128);
}

// One wave per (b, h, s) query. lane = head dim (0..63).
// Q/K/V stored [B*S, DMODEL] row-major (m = b*S+s, col = h*64+d).
__global__ __launch_bounds__(256) void attn_kernel(
    const bf16_t* __restrict__ Q, const bf16_t* __restrict__ K,
    const bf16_t* __restrict__ V, bf16_t* __restrict__ ctx) {
  const int gw = (int)((blockIdx.x * 256 + threadIdx.x) >> 6);
  const int lane = threadIdx.x & 63;
  const int s = gw & (S_LEN - 1);
  const int bh = gw >> 11;  // / S_LEN
  const int h = bh & (NHEADS - 1);
  const int b = bh >> 4;

  const size_t base = ((size_t)(b * S_LEN + s)) * DMODEL + h * HDIM;
  const float q = (float)Q[base + lane];

  float sc[5];
#pragma unroll
  for (int jj = 0; jj < 5; ++jj) {
    const int j = s - 2 + jj;
    if (j < 0 || j >= S_LEN) {  // wave-uniform branch
      sc[jj] = -1e30f;
      continue;
    }
    const size_t kb = ((size_t)(b * S_LEN + j)) * DMODEL + h * HDIM;
    float d = q * (float)K[kb + lane];
#pragma unroll
    for (int off = 32; off > 0; off >>= 1) d += __shfl_xor(d, off);
    sc[jj] = d * 0.125f;  // 1/sqrt(64)
  }

  float m = sc[0];
#pragma unroll
  for (int jj = 1; jj < 5; ++jj) m = fmaxf(m, sc[jj]);
  float p[5], l = 0.f;
#pragma unroll
  for (int jj = 0; jj < 5; ++jj) {
    p[jj] = __expf(sc[jj] - m);  // masked -> exp(-huge) = 0
    l += p[jj];
  }
  const float inv = 1.0f / l;

  float o = 0.f;
#pragma unroll
  for (int jj = 0; jj < 5; ++jj) {
    const int j = s - 2 + jj;
    if (j < 0 || j >= S_LEN) continue;
    const size_t vb = ((size_t)(b * S_LEN + j)) * DMODEL + h * HDIM;
    o += p[jj] * (float)V[vb + lane];
  }
  ctx[base + lane] = (bf16_t)(o * inv);
}

extern "C" void kernel_launch(void* const* d_in, const int* in_sizes, int n_in,
                              void* d_out, int out_size, void* d_ws,
                              size_t ws_size, hipStream_t stream) {
  const float* x = (const float*)d_in[0];
  const float* Wq = (const float*)d_in[1];
  const float* bq = (const float*)d_in[2];
  const float* Wk = (const float*)d_in[3];
  const float* bk = (const float*)d_in[4];
  const float* Wv = (const float*)d_in[5];
  const float* bv = (const float*)d_in[6];
  const float* Wo = (const float*)d_in[7];
  const float* bo = (const float*)d_in[8];
  float* out = (float*)d_out;

  const size_t mat = (size_t)BROWS * DMODEL;   // 4096*1024 = 4.19M
  const size_t wmat = (size_t)DMODEL * DMODEL; // 1024*1024 = 1.05M
  bf16_t* xb = (bf16_t*)d_ws;
  bf16_t* Wqb = xb + mat;
  bf16_t* Wkb = Wqb + wmat;
  bf16_t* Wvb = Wkb + wmat;
  bf16_t* Wob = Wvb + wmat;
  bf16_t* Q = Wob + wmat;
  bf16_t* K = Q + mat;
  bf16_t* V = K + mat;
  bf16_t* ctx = V + mat;
  // total ws: (4.19M*5 + 1.05M*4) * 2B = ~50 MB

  // f32 -> bf16 conversions
  cvt_kernel<<<(int)(mat / 4 / 256), 256, 0, stream>>>(x, xb, (int)(mat / 4));
  cvt_kernel<<<(int)(wmat / 4 / 256), 256, 0, stream>>>(Wq, Wqb, (int)(wmat / 4));
  cvt_kernel<<<(int)(wmat / 4 / 256), 256, 0, stream>>>(Wk, Wkb, (int)(wmat / 4));
  cvt_kernel<<<(int)(wmat / 4 / 256), 256, 0, stream>>>(Wv, Wvb, (int)(wmat / 4));
  cvt_kernel<<<(int)(wmat / 4 / 256), 256, 0, stream>>>(Wo, Wob, (int)(wmat / 4));

  // QKV projections fused: grid 32 x 24 (3 mats x 8 col-tiles)
  gemm_qkv_kernel<<<dim3(32, 24), 256, 0, stream>>>(xb, Wqb, Wkb, Wvb, bq, bk,
                                                    bv, Q, K, V);
  // Local attention: 2*16*2048 = 65536 waves, 4 per block
  attn_kernel<<<16384, 256, 0, stream>>>(Q, K, V, ctx);
  // Output projection: grid 32 x 8, f32 output
  gemm_o_kernel<<<dim3(32, 8), 256, 0, stream>>>(ctx, Wob, bo, out);
}

// Round 3
// 80.192 us; speedup vs baseline: 1.4312x; 1.4312x over previous
//
#include <hip/hip_runtime.h>
#include <hip/hip_bf16.h>

typedef __bf16 bf16_t;
typedef __bf16 bf16x4 __attribute__((ext_vector_type(4)));
typedef __bf16 bf16x8 __attribute__((ext_vector_type(8)));
typedef float f32x4 __attribute__((ext_vector_type(4)));

#define S_LEN 2048
#define DMODEL 1024
#define NHEADS 16
#define HDIM 64
#define BROWS 4096  // B * S

__device__ __forceinline__ void async16(const void* g, void* l) {
  __builtin_amdgcn_global_load_lds(
      (const __attribute__((address_space(1))) void*)g,
      (__attribute__((address_space(3))) void*)l, 16, 0, 0);
}

// ------------- fused f32 -> bf16 conversion (x, Wq, Wk, Wv, Wo) -------------
// dst (ws) is one contiguous bf16 range; src picked by segment.
__global__ __launch_bounds__(256) void cvt_all_kernel(
    const float* __restrict__ x, const float* __restrict__ Wq,
    const float* __restrict__ Wk, const float* __restrict__ Wv,
    const float* __restrict__ Wo, bf16_t* __restrict__ dst) {
  const int i = blockIdx.x * 256 + threadIdx.x;  // float4 index, < 2097152
  constexpr int XN4 = (BROWS * DMODEL) / 4;      // 1048576
  constexpr int WN4 = (DMODEL * DMODEL) / 4;     // 262144
  const float* src;
  size_t off;
  if (i < XN4) {
    src = x;
    off = (size_t)i;
  } else {
    const int wi = i - XN4;
    const int w = wi >> 18;  // /262144
    off = (size_t)(wi & (WN4 - 1));
    src = (w == 0) ? Wq : (w == 1) ? Wk : (w == 2) ? Wv : Wo;
  }
  const float4 v = *(const float4*)(src + off * 4);
  bf16x4 o;
  o[0] = (bf16_t)v.x;
  o[1] = (bf16_t)v.y;
  o[2] = (bf16_t)v.z;
  o[3] = (bf16_t)v.w;
  *(bf16x4*)(dst + (size_t)i * 4) = o;
}

// C[m,n] = sum_k A[m,k] * W[n,k] + bias[n]
// Tile 128x128, BK=32, 4 waves (2x2), each wave 64x64 = 4x4 frags of 16x16x32.
template <typename OutT>
__device__ __forceinline__ void gemm_body(
    const bf16_t* __restrict__ A, const bf16_t* __restrict__ W,
    const float* __restrict__ bias, OutT* __restrict__ C, int m0, int n0) {
  constexpr int Kd = 1024, Nd = 1024, BK = 32, NT = Kd / BK;
  __shared__ bf16_t ldsA[2][128 * BK];
  __shared__ bf16_t ldsB[2][128 * BK];

  const int tid = threadIdx.x;
  const int lane = tid & 63;
  const int wave = tid >> 6;
  const int wr = wave >> 1;
  const int wc = wave & 1;

  f32x4 acc[4][4] = {};

  const int fr = lane & 15;
  const int ko = (lane >> 4) * 8;

  auto stage = [&](int buf, int t) {
    const int k0 = t * BK;
#pragma unroll
    for (int p = 0; p < 2; ++p) {
      const int off = (p * 256 + tid) * 16;
      const int row = off >> 6;
      const int kb = off & 63;
      async16((const char*)(A + (size_t)(m0 + row) * Kd + k0) + kb,
              (char*)ldsA[buf] + off);
      async16((const char*)(W + (size_t)(n0 + row) * Kd + k0) + kb,
              (char*)ldsB[buf] + off);
    }
  };

  auto compute = [&](int buf) {
    bf16x8 af[4], bfr[4];
#pragma unroll
    for (int i = 0; i < 4; ++i)
      af[i] = *(const bf16x8*)(ldsA[buf] + (wr * 64 + i * 16 + fr) * BK + ko);
#pragma unroll
    for (int j = 0; j < 4; ++j)
      bfr[j] = *(const bf16x8*)(ldsB[buf] + (wc * 64 + j * 16 + fr) * BK + ko);
#pragma unroll
    for (int i = 0; i < 4; ++i)
#pragma unroll
      for (int j = 0; j < 4; ++j)
        acc[i][j] = __builtin_amdgcn_mfma_f32_16x16x32_bf16(af[i], bfr[j],
                                                            acc[i][j], 0, 0, 0);
  };

  stage(0, 0);
  __syncthreads();
#pragma unroll 1
  for (int t = 0; t < NT; ++t) {
    if (t + 1 < NT) stage((t + 1) & 1, t + 1);
    compute(t & 1);
    __syncthreads();
  }

  const int cr = (lane >> 4) * 4;
#pragma unroll
  for (int j = 0; j < 4; ++j) {
    const int col = n0 + wc * 64 + j * 16 + fr;
    const float bv = bias[col];
#pragma unroll
    for (int i = 0; i < 4; ++i) {
#pragma unroll
      for (int r = 0; r < 4; ++r) {
        const int row = m0 + wr * 64 + i * 16 + cr + r;
        C[(size_t)row * Nd + col] = (OutT)(acc[i][j][r] + bv);
      }
    }
  }
}

__global__ __launch_bounds__(256) void gemm_qkv_kernel(
    const bf16_t* __restrict__ xb, const bf16_t* __restrict__ Wqb,
    const bf16_t* __restrict__ Wkb, const bf16_t* __restrict__ Wvb,
    const float* __restrict__ bq, const float* __restrict__ bk,
    const float* __restrict__ bv, bf16_t* __restrict__ Q,
    bf16_t* __restrict__ K, bf16_t* __restrict__ V) {
  const int mat = blockIdx.y >> 3;
  const int nt = blockIdx.y & 7;
  const bf16_t* W = (mat == 0) ? Wqb : (mat == 1) ? Wkb : Wvb;
  const float* bias = (mat == 0) ? bq : (mat == 1) ? bk : bv;
  bf16_t* C = (mat == 0) ? Q : (mat == 1) ? K : V;
  gemm_body<bf16_t>(xb, W, bias, C, blockIdx.x * 128, nt * 128);
}

__global__ __launch_bounds__(256) void gemm_o_kernel(
    const bf16_t* __restrict__ ctx, const bf16_t* __restrict__ Wob,
    const float* __restrict__ bo, float* __restrict__ out) {
  gemm_body<float>(ctx, Wob, bo, out, blockIdx.x * 128, blockIdx.y * 128);
}

// ------------------------- local attention (thread-per-query) --------------
// One 256-thread block per (b, h, 256-query chunk). K/V window staged in LDS
// with XOR swizzle (pre-swizzled global source + swizzled read, both-sides).
#define CHUNK 256
#define TROWS 260  // CHUNK + WINDOW - 1 rows staged

__global__ __launch_bounds__(256) void attn_kernel(
    const bf16_t* __restrict__ Q, const bf16_t* __restrict__ K,
    const bf16_t* __restrict__ V, bf16_t* __restrict__ ctx) {
  __shared__ bf16_t ldsK[TROWS * HDIM];
  __shared__ bf16_t ldsV[TROWS * HDIM];

  const int tid = threadIdx.x;
  const int blk = blockIdx.x;   // 0..255
  const int chunk = blk & 7;    // 8 chunks of 256 queries
  const int bh = blk >> 3;      // 0..31
  const int h = bh & (NHEADS - 1);
  const int b = bh >> 4;
  const int s0 = chunk * CHUNK;

  const bf16_t* Kb = K + (size_t)b * S_LEN * DMODEL + h * HDIM;
  const bf16_t* Vb = V + (size_t)b * S_LEN * DMODEL + h * HDIM;

  // ---- stage K/V tiles: logical (row, c) lives at LDS slot (row, c^(row&7))
  // LDS dest is linear (global_load_lds requirement); source is pre-swizzled.
#pragma unroll
  for (int j = 0; j < 9; ++j) {
    const int i = j * 256 + tid;  // 16B chunk index
    if (i < TROWS * 8) {
      const int tr = i >> 3;
      const int slot = i & 7;
      const int c = slot ^ (tr & 7);
      int gs = s0 - 2 + tr;
      gs = (gs < 0) ? 0 : (gs >= S_LEN ? S_LEN - 1 : gs);  // clamped; masked later
      async16((const char*)(Kb + (size_t)gs * DMODEL) + c * 16,
              (char*)ldsK + i * 16);
      async16((const char*)(Vb + (size_t)gs * DMODEL) + c * 16,
              (char*)ldsV + i * 16);
    }
  }

  // ---- load own Q row (overlaps with staging), convert to f32
  const int s = s0 + tid;
  const bf16_t* Qrow = Q + ((size_t)(b * S_LEN) + s) * DMODEL + h * HDIM;
  bf16x8 q8[8];
#pragma unroll
  for (int c = 0; c < 8; ++c) q8[c] = *(const bf16x8*)(Qrow + c * 8);
  float qf[64];
#pragma unroll
  for (int c = 0; c < 8; ++c)
#pragma unroll
    for (int e = 0; e < 8; ++e) qf[c * 8 + e] = (float)q8[c][e];

  __syncthreads();  // drains vmcnt -> staged tiles visible

  // ---- scores (5 serial dots from LDS, swizzled read)
  float sc[5];
#pragma unroll
  for (int jj = 0; jj < 5; ++jj) {
    const int tr = tid + jj;  // logical tile row = key (s0-2+tr)
    float d = 0.f;
#pragma unroll
    for (int c = 0; c < 8; ++c) {
      const bf16x8 k8 =
          *(const bf16x8*)(ldsK + tr * HDIM + (c ^ (tr & 7)) * 8);
#pragma unroll
      for (int e = 0; e < 8; ++e) d += qf[c * 8 + e] * (float)k8[e];
    }
    const int j = s - 2 + jj;
    sc[jj] = (j < 0 || j >= S_LEN) ? -1e30f : d * 0.125f;  // 1/sqrt(64)
  }

  // ---- softmax over 5
  float m = sc[0];
#pragma unroll
  for (int jj = 1; jj < 5; ++jj) m = fmaxf(m, sc[jj]);
  float p[5], l = 0.f;
#pragma unroll
  for (int jj = 0; jj < 5; ++jj) {
    p[jj] = __expf(sc[jj] - m);
    l += p[jj];
  }
  const float inv = 1.0f / l;
#pragma unroll
  for (int jj = 0; jj < 5; ++jj) p[jj] *= inv;

  // ---- PV accumulate
  float o[64];
#pragma unroll
  for (int e = 0; e < 64; ++e) o[e] = 0.f;
#pragma unroll
  for (int jj = 0; jj < 5; ++jj) {
    const int tr = tid + jj;
    const float pj = p[jj];
#pragma unroll
    for (int c = 0; c < 8; ++c) {
      const bf16x8 v8 =
          *(const bf16x8*)(ldsV + tr * HDIM + (c ^ (tr & 7)) * 8);
#pragma unroll
      for (int e = 0; e < 8; ++e) o[c * 8 + e] += pj * (float)v8[e];
    }
  }

  // ---- store ctx row (bf16, vectorized)
  bf16_t* Crow = (bf16_t*)ctx + ((size_t)(b * S_LEN) + s) * DMODEL + h * HDIM;
#pragma unroll
  for (int c = 0; c < 8; ++c) {
    bf16x8 ov;
#pragma unroll
    for (int e = 0; e < 8; ++e) ov[e] = (bf16_t)o[c * 8 + e];
    *(bf16x8*)(Crow + c * 8) = ov;
  }
}

extern "C" void kernel_launch(void* const* d_in, const int* in_sizes, int n_in,
                              void* d_out, int out_size, void* d_ws,
                              size_t ws_size, hipStream_t stream) {
  const float* x = (const float*)d_in[0];
  const float* Wq = (const float*)d_in[1];
  const float* bq = (const float*)d_in[2];
  const float* Wk = (const float*)d_in[3];
  const float* bk = (const float*)d_in[4];
  const float* Wv = (const float*)d_in[5];
  const float* bv = (const float*)d_in[6];
  const float* Wo = (const float*)d_in[7];
  const float* bo = (const float*)d_in[8];
  float* out = (float*)d_out;

  const size_t mat = (size_t)BROWS * DMODEL;    // 4.19M
  const size_t wmat = (size_t)DMODEL * DMODEL;  // 1.05M
  bf16_t* xb = (bf16_t*)d_ws;  // [xb | Wqb | Wkb | Wvb | Wob] contiguous
  bf16_t* Wqb = xb + mat;
  bf16_t* Wkb = Wqb + wmat;
  bf16_t* Wvb = Wkb + wmat;
  bf16_t* Wob = Wvb + wmat;
  bf16_t* Q = Wob + wmat;
  bf16_t* K = Q + mat;
  bf16_t* V = K + mat;
  bf16_t* ctx = V + mat;

  // single fused conversion: (mat + 4*wmat)/4 float4s = 2097152 -> 8192 blocks
  cvt_all_kernel<<<8192, 256, 0, stream>>>(x, Wq, Wk, Wv, Wo, xb);

  gemm_qkv_kernel<<<dim3(32, 24), 256, 0, stream>>>(xb, Wqb, Wkb, Wvb, bq, bk,
                                                    bv, Q, K, V);
  attn_kernel<<<256, 256, 0, stream>>>(Q, K, V, ctx);
  gemm_o_kernel<<<dim3(32, 8), 256, 0, stream>>>(ctx, Wob, bo, out);
}